// Round 1
// baseline (348.582 us; speedup 1.0000x reference)
//
#include <hip/hip_runtime.h>
#include <math.h>

// Problem constants (fixed by setup_inputs)
#define BN_ 16
#define C_ 128
#define H_ 64
#define W_ 64
#define G_ 4
#define HS_ 128
#define WS_ 128
#define CG_ 32
#define HW_ (H_*W_)     // 4096
#define HWS_ (HS_*WS_)  // 16384
#define NOFF_ (BN_*8*HW_) // 524288

// ---------------------------------------------------------------------------
// Kernel 0: fold BN into 1x1 weights, transpose to [k][co]; compute fused bias
// ---------------------------------------------------------------------------
__global__ void prep_w(const float* __restrict__ w_proj, const float* __restrict__ g,
                       const float* __restrict__ be, const float* __restrict__ mean,
                       const float* __restrict__ var, float* __restrict__ wT,
                       float* __restrict__ b2) {
    int i = blockIdx.x * 256 + threadIdx.x;
    if (i < C_ * C_) {
        int k = i >> 7, co = i & 127;
        float a = g[co] / sqrtf(var[co] + 1e-5f);
        wT[i] = w_proj[co * C_ + k] * a;
    } else if (i < C_ * C_ + C_) {
        int co = i - C_ * C_;
        float a = g[co] / sqrtf(var[co] + 1e-5f);
        b2[co] = be[co] - mean[co] * a;
    }
}

// ---------------------------------------------------------------------------
// Kernel 1: 3x3 conv (offset branch), C split into 4 chunks across blocks.
// Block: 256 threads = 16 rows x 16 col-groups(4 px each). Covers 16 rows x 64
// cols of one batch image for one 32-channel chunk; all 8 output channels.
// Writes partial sums to part[cc][b][co][h][w].
// ---------------------------------------------------------------------------
__global__ __launch_bounds__(256) void conv_off(const float* __restrict__ x,
                                                const float* __restrict__ w_off,
                                                float* __restrict__ part) {
    int bx = blockIdx.x;            // 256 blocks
    int cc = bx & 3;                // channel chunk (32 ch)
    int rt = (bx >> 2) & 3;         // row tile (16 rows)
    int b  = bx >> 4;               // batch
    int t = threadIdx.x;
    int rloc = t >> 4;              // 0..15 (output row in tile)
    int cb   = (t & 15) * 4;        // output col base

    __shared__ float xs[4][18][67]; // 4 ch x 18 rows x (66 cols stored at +1), stride 67 vs bank conflicts
    __shared__ float wsh[8][4][9];

    float acc[8][4];
#pragma unroll
    for (int i = 0; i < 8; ++i)
#pragma unroll
        for (int j = 0; j < 4; ++j) acc[i][j] = 0.f;

    int row0 = rt * 16;

    for (int sub = 0; sub < 8; ++sub) {
        int cbase = cc * 32 + sub * 4;
        __syncthreads();
        // stage x tile: 4 ch x 18 rows x 66 cols (col -1..64), zero-padded
        for (int i = t; i < 4 * 18 * 66; i += 256) {
            int ch  = i / (18 * 66);
            int rem = i % (18 * 66);
            int r   = rem / 66;
            int ci  = rem % 66;       // stored index
            int col = ci - 1;         // global col
            int grow = row0 + r - 1;  // global row
            float v = 0.f;
            if (col >= 0 && col < W_ && grow >= 0 && grow < H_)
                v = x[((b * C_ + cbase + ch) * H_ + grow) * W_ + col];
            xs[ch][r][ci] = v;
        }
        // stage weights: 8 co x 4 ch x 9 taps
        for (int i = t; i < 8 * 4 * 9; i += 256) {
            int co = i / 36;
            int r  = i % 36;
            int ch = r / 9, tap = r % 9;
            wsh[co][ch][tap] = w_off[(co * C_ + cbase + ch) * 9 + tap];
        }
        __syncthreads();
#pragma unroll
        for (int ch = 0; ch < 4; ++ch) {
#pragma unroll
            for (int ky = 0; ky < 3; ++ky) {
                float wv[3][8];
#pragma unroll
                for (int kx = 0; kx < 3; ++kx)
#pragma unroll
                    for (int co = 0; co < 8; ++co)
                        wv[kx][co] = wsh[co][ch][ky * 3 + kx];
                float xv[6];
#pragma unroll
                for (int j = 0; j < 6; ++j) xv[j] = xs[ch][rloc + ky][cb + j];
#pragma unroll
                for (int px = 0; px < 4; ++px)
#pragma unroll
                    for (int kx = 0; kx < 3; ++kx) {
                        float xval = xv[px + kx];
#pragma unroll
                        for (int co = 0; co < 8; ++co)
                            acc[co][px] += xval * wv[kx][co];
                    }
            }
        }
    }
#pragma unroll
    for (int co = 0; co < 8; ++co) {
        float4 v = make_float4(acc[co][0], acc[co][1], acc[co][2], acc[co][3]);
        *(float4*)&part[((size_t)(cc * BN_ + b) * 8 + co) * HW_ + (row0 + rloc) * W_ + cb] = v;
    }
}

// ---------------------------------------------------------------------------
// Kernel 2: reduce 4 partials + bias + tanh -> off
// ---------------------------------------------------------------------------
__global__ void off_reduce(const float* __restrict__ part, const float* __restrict__ b_off,
                           float* __restrict__ off) {
    int i = (blockIdx.x * 256 + threadIdx.x) * 4;
    if (i >= NOFF_) return;
    float4 a0 = *(const float4*)&part[i];
    float4 a1 = *(const float4*)&part[NOFF_ + i];
    float4 a2 = *(const float4*)&part[2 * NOFF_ + i];
    float4 a3 = *(const float4*)&part[3 * NOFF_ + i];
    int co = (i / HW_) & 7;
    float bb = b_off[co];
    float4 r;
    r.x = tanhf(a0.x + a1.x + a2.x + a3.x + bb);
    r.y = tanhf(a0.y + a1.y + a2.y + a3.y + bb);
    r.z = tanhf(a0.z + a1.z + a2.z + a3.z + bb);
    r.w = tanhf(a0.w + a1.w + a2.w + a3.w + bb);
    *(float4*)&off[i] = r;
}

// ---------------------------------------------------------------------------
// Kernel 3: 1x1 conv + folded BN + SiLU -> p. GEMM-like: block = 64 pos x 128 co.
// Thread: 8 co x 4 pos accumulators.
// ---------------------------------------------------------------------------
__global__ __launch_bounds__(256) void conv_proj(const float* __restrict__ x,
                                                 const float* __restrict__ wT,
                                                 const float* __restrict__ b2,
                                                 float* __restrict__ p) {
    int bx = blockIdx.x;            // 1024 blocks
    int b = bx >> 6;
    int pos0 = (bx & 63) * 64;
    int t = threadIdx.x;
    int cob = (t >> 4) * 8;         // 0,8,...,120
    int pb  = (t & 15) * 4;         // 0,4,...,60

    __shared__ float xs[16][64];
    __shared__ float wsh[16][128];

    float4 acc[8];
#pragma unroll
    for (int i = 0; i < 8; ++i) acc[i] = make_float4(0.f, 0.f, 0.f, 0.f);

    for (int k0 = 0; k0 < C_; k0 += 16) {
        __syncthreads();
        {
            int i = t * 4;
            int k = i >> 6, pos = i & 63;
            *(float4*)&xs[k][pos] = *(const float4*)&x[(size_t)(b * C_ + k0 + k) * HW_ + pos0 + pos];
            int j = t * 8;
            int kk = j >> 7, co = j & 127;
            *(float4*)&wsh[kk][co]     = *(const float4*)&wT[(k0 + kk) * C_ + co];
            *(float4*)&wsh[kk][co + 4] = *(const float4*)&wT[(k0 + kk) * C_ + co + 4];
        }
        __syncthreads();
#pragma unroll
        for (int k = 0; k < 16; ++k) {
            float4 xv = *(float4*)&xs[k][pb];
            float4 w0 = *(float4*)&wsh[k][cob];
            float4 w1 = *(float4*)&wsh[k][cob + 4];
            float wa[8] = {w0.x, w0.y, w0.z, w0.w, w1.x, w1.y, w1.z, w1.w};
#pragma unroll
            for (int co = 0; co < 8; ++co) {
                acc[co].x += wa[co] * xv.x;
                acc[co].y += wa[co] * xv.y;
                acc[co].z += wa[co] * xv.z;
                acc[co].w += wa[co] * xv.w;
            }
        }
    }
#pragma unroll
    for (int co = 0; co < 8; ++co) {
        float bb = b2[cob + co];
        float4 v = acc[co];
        v.x += bb; v.y += bb; v.z += bb; v.w += bb;
        v.x = v.x / (1.f + expf(-v.x));
        v.y = v.y / (1.f + expf(-v.y));
        v.z = v.z / (1.f + expf(-v.z));
        v.w = v.w / (1.f + expf(-v.w));
        *(float4*)&p[(size_t)(b * C_ + cob + co) * HW_ + pos0 + pb] = v;
    }
}

// ---------------------------------------------------------------------------
// Kernel 4: upsample offsets + grid_sample + write out.
// Block = one output row (128 px) for one (b,g); thread = one xs; loop 32 ch.
// ---------------------------------------------------------------------------
__global__ __launch_bounds__(128) void dysample(const float* __restrict__ p,
                                                const float* __restrict__ off,
                                                float* __restrict__ out) {
    int bx = blockIdx.x;            // B*G*HS = 8192
    int ys = bx & 127;
    int g  = (bx >> 7) & 3;
    int b  = bx >> 9;
    int xsid = threadIdx.x;         // 0..127

    const float rw = 63.0f / 127.0f;
    float py = ys * rw;
    int uy0 = (int)floorf(py);
    float fy = py - (float)uy0;
    int uy1 = min(uy0 + 1, 63);
    float pxf = xsid * rw;
    int ux0 = (int)floorf(pxf);
    float fx = pxf - (float)ux0;
    int ux1 = min(ux0 + 1, 63);

    const float* o0 = off + (size_t)(b * 8 + 2 * g) * HW_;
    const float* o1 = o0 + HW_;
    float ox, oy;
    {
        float a00 = o0[uy0 * 64 + ux0], a01 = o0[uy0 * 64 + ux1];
        float a10 = o0[uy1 * 64 + ux0], a11 = o0[uy1 * 64 + ux1];
        float t0 = a00 * (1.f - fy) + a10 * fy;
        float t1 = a01 * (1.f - fy) + a11 * fy;
        ox = t0 * (1.f - fx) + t1 * fx;
    }
    {
        float a00 = o1[uy0 * 64 + ux0], a01 = o1[uy0 * 64 + ux1];
        float a10 = o1[uy1 * 64 + ux0], a11 = o1[uy1 * 64 + ux1];
        float t0 = a00 * (1.f - fy) + a10 * fy;
        float t1 = a01 * (1.f - fy) + a11 * fy;
        oy = t0 * (1.f - fx) + t1 * fx;
    }

    float gx = (-1.f + xsid * (2.0f / 127.0f)) + ox * (2.0f / 128.0f);
    float gy = (-1.f + ys   * (2.0f / 127.0f)) + oy * (2.0f / 128.0f);

    float ix = fminf(fmaxf((gx + 1.f) * 0.5f * 63.f, 0.f), 63.f);
    float iy = fminf(fmaxf((gy + 1.f) * 0.5f * 63.f, 0.f), 63.f);
    int sx0 = (int)floorf(ix);
    int sx1 = min(sx0 + 1, 63);
    float wx = ix - (float)sx0;
    int sy0 = (int)floorf(iy);
    int sy1 = min(sy0 + 1, 63);
    float wy = iy - (float)sy0;

    int o00 = sy0 * 64 + sx0, o01 = sy0 * 64 + sx1;
    int o10 = sy1 * 64 + sx0, o11 = sy1 * 64 + sx1;
    const float* pbase = p + (size_t)(b * C_ + g * CG_) * HW_;
    float* obase = out + (size_t)(b * C_ + g * CG_) * HWS_ + ys * WS_ + xsid;
#pragma unroll 4
    for (int c = 0; c < CG_; ++c) {
        const float* pc = pbase + (size_t)c * HW_;
        float v00 = pc[o00], v01 = pc[o01], v10 = pc[o10], v11 = pc[o11];
        float r = (v00 * (1.f - wx) + v01 * wx) * (1.f - wy)
                + (v10 * (1.f - wx) + v11 * wx) * wy;
        obase[(size_t)c * HWS_] = r;
    }
}

// ---------------------------------------------------------------------------
extern "C" void kernel_launch(void* const* d_in, const int* in_sizes, int n_in,
                              void* d_out, int out_size, void* d_ws, size_t ws_size,
                              hipStream_t stream) {
    const float* x      = (const float*)d_in[0];
    const float* w_off  = (const float*)d_in[1];
    const float* b_off  = (const float*)d_in[2];
    const float* w_proj = (const float*)d_in[3];
    const float* bn_g   = (const float*)d_in[4];
    const float* bn_b   = (const float*)d_in[5];
    const float* bn_m   = (const float*)d_in[6];
    const float* bn_v   = (const float*)d_in[7];
    float* out = (float*)d_out;
    float* ws  = (float*)d_ws;

    // ws layout (floats):
    float* p    = ws;                 // 8,388,608 (B*C*H*W)
    float* part = ws + 8388608;       // 2,097,152 (4 chunks x B*8*H*W)
    float* offb = ws + 10485760;      //   524,288
    float* wT   = ws + 11010048;      //    16,384
    float* b2   = ws + 11026432;      //       128   (total ~44.1 MB)

    prep_w    <<<65,   256, 0, stream>>>(w_proj, bn_g, bn_b, bn_m, bn_v, wT, b2);
    conv_off  <<<256,  256, 0, stream>>>(x, w_off, part);
    off_reduce<<<512,  256, 0, stream>>>(part, b_off, offb);
    conv_proj <<<1024, 256, 0, stream>>>(x, wT, b2, p);
    dysample  <<<8192, 128, 0, stream>>>(p, offb, out);
}

// Round 2
// 265.205 us; speedup vs baseline: 1.3144x; 1.3144x over previous
//
#include <hip/hip_runtime.h>
#include <math.h>

// Problem constants (fixed by setup_inputs)
#define BN_ 16
#define C_ 128
#define H_ 64
#define W_ 64
#define G_ 4
#define HS_ 128
#define WS_ 128
#define CG_ 32
#define HW_ (H_*W_)       // 4096
#define HWS_ (HS_*WS_)    // 16384
#define NOFF_ (BN_*8*HW_) // 524288

// ---------------------------------------------------------------------------
// Kernel 0: fold BN into 1x1 weights, transpose to [k][co]; fused bias
// ---------------------------------------------------------------------------
__global__ void prep_w(const float* __restrict__ w_proj, const float* __restrict__ g,
                       const float* __restrict__ be, const float* __restrict__ mean,
                       const float* __restrict__ var, float* __restrict__ wT,
                       float* __restrict__ b2) {
    int i = blockIdx.x * 256 + threadIdx.x;
    if (i < C_ * C_) {
        int k = i >> 7, co = i & 127;
        float a = g[co] / sqrtf(var[co] + 1e-5f);
        wT[i] = w_proj[co * C_ + k] * a;
    } else if (i < C_ * C_ + C_) {
        int co = i - C_ * C_;
        float a = g[co] / sqrtf(var[co] + 1e-5f);
        b2[co] = be[co] - mean[co] * a;
    }
}

// ---------------------------------------------------------------------------
// Kernel 1: 3x3 conv (offset branch).
// Grid 1024 = 16 b x 8 row-tiles(8 rows) x 8 channel-chunks(16 ch).
// Block 256 thr = 8 rows x 32 colgroups(2 px). 2 sub-iterations of 8 channels.
// Weights in LDS as [ch][tap][co0..7] -> wave-uniform float4 broadcast reads.
// x tile in LDS [ch][10 rows][66 cols] (col+1 shift, zero-padded halo).
// ---------------------------------------------------------------------------
__global__ __launch_bounds__(256) void conv_off(const float* __restrict__ x,
                                                const float* __restrict__ w_off,
                                                float* __restrict__ part) {
    int bx = blockIdx.x;
    int cc = bx & 7;
    int rt = (bx >> 3) & 7;
    int b  = bx >> 6;
    int t  = threadIdx.x;
    int row = t >> 5;             // 0..7
    int cb  = (t & 31) * 2;       // 0..62

    __shared__ float xs[8][10][66];
    __shared__ float wsh[8][9][8];   // [ch][tap][co]

    float acc[8][2];
#pragma unroll
    for (int i = 0; i < 8; ++i) { acc[i][0] = 0.f; acc[i][1] = 0.f; }

    int row0 = rt * 8;
    int ch_s = (t >> 4) & 7;
    int q_s  = t & 15;
    int rbase = (t >> 7) * 5;

    for (int sub = 0; sub < 2; ++sub) {
        int cbase = cc * 16 + sub * 8;
        __syncthreads();
        // stage x: each thread 5 float4 rows-quads
#pragma unroll
        for (int it = 0; it < 5; ++it) {
            int r = rbase + it;              // 0..9
            int grow = row0 + r - 1;
            float4 v = make_float4(0.f, 0.f, 0.f, 0.f);
            if (grow >= 0 && grow < H_)
                v = *(const float4*)&x[((size_t)(b * C_ + cbase + ch_s) * H_ + grow) * W_ + q_s * 4];
            xs[ch_s][r][1 + q_s * 4] = v.x;
            xs[ch_s][r][2 + q_s * 4] = v.y;
            xs[ch_s][r][3 + q_s * 4] = v.z;
            xs[ch_s][r][4 + q_s * 4] = v.w;
        }
        if (t < 128) {
            int ch2 = t >> 4, r2 = t & 15;
            if (r2 < 10) { xs[ch2][r2][0] = 0.f; xs[ch2][r2][65] = 0.f; }
        }
        // stage weights: 8ch * 9tap * 8co = 576
        for (int i = t; i < 576; i += 256) {
            int co  = i & 7;
            int tap = (i >> 3) % 9;
            int ch3 = (i >> 3) / 9;
            wsh[ch3][tap][co] = w_off[(co * C_ + cbase + ch3) * 9 + tap];
        }
        __syncthreads();
#pragma unroll
        for (int ch = 0; ch < 8; ++ch) {
#pragma unroll
            for (int ky = 0; ky < 3; ++ky) {
                float2 xv01 = *(float2*)&xs[ch][row + ky][cb];
                float2 xv23 = *(float2*)&xs[ch][row + ky][cb + 2];
                float xa[4] = {xv01.x, xv01.y, xv23.x, xv23.y};
#pragma unroll
                for (int kx = 0; kx < 3; ++kx) {
                    float4 w0 = *(float4*)&wsh[ch][ky * 3 + kx][0];
                    float4 w1 = *(float4*)&wsh[ch][ky * 3 + kx][4];
                    float wv[8] = {w0.x, w0.y, w0.z, w0.w, w1.x, w1.y, w1.z, w1.w};
                    float x0 = xa[kx], x1 = xa[kx + 1];
#pragma unroll
                    for (int co = 0; co < 8; ++co) {
                        acc[co][0] += x0 * wv[co];
                        acc[co][1] += x1 * wv[co];
                    }
                }
            }
        }
    }
#pragma unroll
    for (int co = 0; co < 8; ++co) {
        float2 v = make_float2(acc[co][0], acc[co][1]);
        *(float2*)&part[((size_t)(cc * BN_ + b) * 8 + co) * HW_ + (row0 + row) * W_ + cb] = v;
    }
}

// ---------------------------------------------------------------------------
// Kernel 2: reduce 8 partials + bias + tanh -> off
// ---------------------------------------------------------------------------
__global__ void off_reduce(const float* __restrict__ part, const float* __restrict__ b_off,
                           float* __restrict__ off) {
    int i = (blockIdx.x * 256 + threadIdx.x) * 4;
    if (i >= NOFF_) return;
    float4 s = *(const float4*)&part[i];
#pragma unroll
    for (int j = 1; j < 8; ++j) {
        float4 a = *(const float4*)&part[(size_t)j * NOFF_ + i];
        s.x += a.x; s.y += a.y; s.z += a.z; s.w += a.w;
    }
    int co = (i / HW_) & 7;
    float bb = b_off[co];
    float4 r;
    r.x = tanhf(s.x + bb);
    r.y = tanhf(s.y + bb);
    r.z = tanhf(s.z + bb);
    r.w = tanhf(s.w + bb);
    *(float4*)&off[i] = r;
}

// ---------------------------------------------------------------------------
// Kernel 3: 1x1 conv + folded BN + SiLU -> p.
// Block = 128 co x 128 pos (grid 512 = 16 b x 32 pos-tiles).
// Thread = 8 co (contig) x 8 pos (4+4 split at stride 64 -> conflict-free b128).
// ---------------------------------------------------------------------------
__global__ __launch_bounds__(256) void conv_proj(const float* __restrict__ x,
                                                 const float* __restrict__ wT,
                                                 const float* __restrict__ b2,
                                                 float* __restrict__ p) {
    int bx = blockIdx.x;            // 512 blocks
    int b = bx >> 5;
    int pos0 = (bx & 31) * 128;
    int t = threadIdx.x;
    int cob = (t >> 4) * 8;         // 0..120
    int pb0 = (t & 15) * 4;         // 0..60  (second half at +64)

    __shared__ float xs[16][128];
    __shared__ float wsh[16][128];

    float acc[8][8];
#pragma unroll
    for (int i = 0; i < 8; ++i)
#pragma unroll
        for (int j = 0; j < 8; ++j) acc[i][j] = 0.f;

    for (int k0 = 0; k0 < C_; k0 += 16) {
        __syncthreads();
        // stage: two conflict-free float4 writes per thread per array
#pragma unroll
        for (int j = 0; j < 2; ++j) {
            int idx = j * 1024 + t * 4;
            int k = idx >> 7, pp = idx & 127;
            *(float4*)&xs[k][pp]  = *(const float4*)&x[(size_t)(b * C_ + k0 + k) * HW_ + pos0 + pp];
            *(float4*)&wsh[k][pp] = *(const float4*)&wT[(k0 + k) * C_ + pp];
        }
        __syncthreads();
#pragma unroll
        for (int k = 0; k < 16; ++k) {
            float4 xv0 = *(float4*)&xs[k][pb0];
            float4 xv1 = *(float4*)&xs[k][pb0 + 64];
            float4 w0  = *(float4*)&wsh[k][cob];
            float4 w1  = *(float4*)&wsh[k][cob + 4];
            float xa[8] = {xv0.x, xv0.y, xv0.z, xv0.w, xv1.x, xv1.y, xv1.z, xv1.w};
            float wa[8] = {w0.x, w0.y, w0.z, w0.w, w1.x, w1.y, w1.z, w1.w};
#pragma unroll
            for (int co = 0; co < 8; ++co)
#pragma unroll
                for (int j = 0; j < 8; ++j)
                    acc[co][j] += wa[co] * xa[j];
        }
    }
#pragma unroll
    for (int co = 0; co < 8; ++co) {
        float bb = b2[cob + co];
        float v[8];
#pragma unroll
        for (int j = 0; j < 8; ++j) {
            float a = acc[co][j] + bb;
            v[j] = a / (1.f + __expf(-a));
        }
        float* dst = &p[(size_t)(b * C_ + cob + co) * HW_ + pos0];
        *(float4*)&dst[pb0]      = make_float4(v[0], v[1], v[2], v[3]);
        *(float4*)&dst[pb0 + 64] = make_float4(v[4], v[5], v[6], v[7]);
    }
}

// ---------------------------------------------------------------------------
// Kernel 4: upsample offsets + grid_sample + write out (nontemporal stores).
// Grid 4096 = 16 b x 4 g x 64 row-pairs; block 256 = 2 rows x 128 xs.
// ---------------------------------------------------------------------------
__global__ __launch_bounds__(256) void dysample(const float* __restrict__ p,
                                                const float* __restrict__ off,
                                                float* __restrict__ out) {
    int bx = blockIdx.x;
    int t  = threadIdx.x;
    int ys = (bx & 63) * 2 + (t >> 7);
    int g  = (bx >> 6) & 3;
    int b  = bx >> 8;
    int xsid = t & 127;

    const float rw = 63.0f / 127.0f;
    float py = ys * rw;
    int uy0 = (int)floorf(py);
    float fy = py - (float)uy0;
    int uy1 = min(uy0 + 1, 63);
    float pxf = xsid * rw;
    int ux0 = (int)floorf(pxf);
    float fx = pxf - (float)ux0;
    int ux1 = min(ux0 + 1, 63);

    const float* o0 = off + (size_t)(b * 8 + 2 * g) * HW_;
    const float* o1 = o0 + HW_;
    float ox, oy;
    {
        float a00 = o0[uy0 * 64 + ux0], a01 = o0[uy0 * 64 + ux1];
        float a10 = o0[uy1 * 64 + ux0], a11 = o0[uy1 * 64 + ux1];
        float t0 = a00 * (1.f - fy) + a10 * fy;
        float t1 = a01 * (1.f - fy) + a11 * fy;
        ox = t0 * (1.f - fx) + t1 * fx;
    }
    {
        float a00 = o1[uy0 * 64 + ux0], a01 = o1[uy0 * 64 + ux1];
        float a10 = o1[uy1 * 64 + ux0], a11 = o1[uy1 * 64 + ux1];
        float t0 = a00 * (1.f - fy) + a10 * fy;
        float t1 = a01 * (1.f - fy) + a11 * fy;
        oy = t0 * (1.f - fx) + t1 * fx;
    }

    float gx = (-1.f + xsid * (2.0f / 127.0f)) + ox * (2.0f / 128.0f);
    float gy = (-1.f + ys   * (2.0f / 127.0f)) + oy * (2.0f / 128.0f);

    float ix = fminf(fmaxf((gx + 1.f) * 0.5f * 63.f, 0.f), 63.f);
    float iy = fminf(fmaxf((gy + 1.f) * 0.5f * 63.f, 0.f), 63.f);
    int sx0 = (int)floorf(ix);
    int sx1 = min(sx0 + 1, 63);
    float wx = ix - (float)sx0;
    int sy0 = (int)floorf(iy);
    int sy1 = min(sy0 + 1, 63);
    float wy = iy - (float)sy0;

    int o00 = sy0 * 64 + sx0, o01 = sy0 * 64 + sx1;
    int o10 = sy1 * 64 + sx0, o11 = sy1 * 64 + sx1;
    const float* pbase = p + (size_t)(b * C_ + g * CG_) * HW_;
    float* obase = out + (size_t)(b * C_ + g * CG_) * HWS_ + ys * WS_ + xsid;
    float w00 = (1.f - wx) * (1.f - wy), w01 = wx * (1.f - wy);
    float w10 = (1.f - wx) * wy,         w11 = wx * wy;
#pragma unroll 4
    for (int c = 0; c < CG_; ++c) {
        const float* pc = pbase + (size_t)c * HW_;
        float r = pc[o00] * w00 + pc[o01] * w01 + pc[o10] * w10 + pc[o11] * w11;
        __builtin_nontemporal_store(r, &obase[(size_t)c * HWS_]);
    }
}

// ---------------------------------------------------------------------------
extern "C" void kernel_launch(void* const* d_in, const int* in_sizes, int n_in,
                              void* d_out, int out_size, void* d_ws, size_t ws_size,
                              hipStream_t stream) {
    const float* x      = (const float*)d_in[0];
    const float* w_off  = (const float*)d_in[1];
    const float* b_off  = (const float*)d_in[2];
    const float* w_proj = (const float*)d_in[3];
    const float* bn_g   = (const float*)d_in[4];
    const float* bn_b   = (const float*)d_in[5];
    const float* bn_m   = (const float*)d_in[6];
    const float* bn_v   = (const float*)d_in[7];
    float* out = (float*)d_out;
    float* ws  = (float*)d_ws;

    // ws layout (floats). part (16MB) is dead before p (32MB) is written -> alias.
    float* p    = ws;                 // 8,388,608 floats
    float* part = ws;                 // 4,194,304 floats (aliased with p)
    float* offb = ws + 8388608;       //   524,288
    float* wT   = ws + 8912896;       //    16,384
    float* b2   = ws + 8929280;       //       128   (total ~35.7 MB)

    prep_w    <<<65,   256, 0, stream>>>(w_proj, bn_g, bn_b, bn_m, bn_v, wT, b2);
    conv_off  <<<1024, 256, 0, stream>>>(x, w_off, part);
    off_reduce<<<512,  256, 0, stream>>>(part, b_off, offb);
    conv_proj <<<512,  256, 0, stream>>>(x, wT, b2, p);
    dysample  <<<4096, 256, 0, stream>>>(p, offb, out);
}

// Round 8
// 244.086 us; speedup vs baseline: 1.4281x; 1.0865x over previous
//
#include <hip/hip_runtime.h>
#include <math.h>

// Problem constants (fixed by setup_inputs)
#define BN_ 16
#define C_ 128
#define H_ 64
#define W_ 64
#define G_ 4
#define HS_ 128
#define WS_ 128
#define CG_ 32
#define HW_ (H_*W_)       // 4096
#define HWS_ (HS_*WS_)    // 16384
#define NOFF_ (BN_*8*HW_) // 524288

// ---------------------------------------------------------------------------
// Kernel 0: fold BN into 1x1 weights, transpose to [k][co]; fused bias
// ---------------------------------------------------------------------------
__global__ void prep_w(const float* __restrict__ w_proj, const float* __restrict__ g,
                       const float* __restrict__ be, const float* __restrict__ mean,
                       const float* __restrict__ var, float* __restrict__ wT,
                       float* __restrict__ b2) {
    int i = blockIdx.x * 256 + threadIdx.x;
    if (i < C_ * C_) {
        int k = i >> 7, co = i & 127;
        float a = g[co] / sqrtf(var[co] + 1e-5f);
        wT[i] = w_proj[co * C_ + k] * a;
    } else if (i < C_ * C_ + C_) {
        int co = i - C_ * C_;
        float a = g[co] / sqrtf(var[co] + 1e-5f);
        b2[co] = be[co] - mean[co] * a;
    }
}

// ---------------------------------------------------------------------------
// Kernel 1: 3x3 conv (offset branch).
// Grid 1024 = 16 b x 8 row-tiles(8 rows) x 8 channel-chunks(16 ch).
// Block 256 thr = 8 rows x 32 colgroups(2 px). 2 sub-iterations of 8 channels.
// ---------------------------------------------------------------------------
__global__ __launch_bounds__(256) void conv_off(const float* __restrict__ x,
                                                const float* __restrict__ w_off,
                                                float* __restrict__ part) {
    int bx = blockIdx.x;
    int cc = bx & 7;
    int rt = (bx >> 3) & 7;
    int b  = bx >> 6;
    int t  = threadIdx.x;
    int row = t >> 5;             // 0..7
    int cb  = (t & 31) * 2;       // 0..62

    __shared__ float xs[8][10][66];
    __shared__ float wsh[8][9][8];   // [ch][tap][co]

    float acc[8][2];
#pragma unroll
    for (int i = 0; i < 8; ++i) { acc[i][0] = 0.f; acc[i][1] = 0.f; }

    int row0 = rt * 8;
    int ch_s = (t >> 4) & 7;
    int q_s  = t & 15;
    int rbase = (t >> 7) * 5;

    for (int sub = 0; sub < 2; ++sub) {
        int cbase = cc * 16 + sub * 8;
        __syncthreads();
#pragma unroll
        for (int it = 0; it < 5; ++it) {
            int r = rbase + it;              // 0..9
            int grow = row0 + r - 1;
            float4 v = make_float4(0.f, 0.f, 0.f, 0.f);
            if (grow >= 0 && grow < H_)
                v = *(const float4*)&x[((size_t)(b * C_ + cbase + ch_s) * H_ + grow) * W_ + q_s * 4];
            xs[ch_s][r][1 + q_s * 4] = v.x;
            xs[ch_s][r][2 + q_s * 4] = v.y;
            xs[ch_s][r][3 + q_s * 4] = v.z;
            xs[ch_s][r][4 + q_s * 4] = v.w;
        }
        if (t < 128) {
            int ch2 = t >> 4, r2 = t & 15;
            if (r2 < 10) { xs[ch2][r2][0] = 0.f; xs[ch2][r2][65] = 0.f; }
        }
        for (int i = t; i < 576; i += 256) {
            int co  = i & 7;
            int tap = (i >> 3) % 9;
            int ch3 = (i >> 3) / 9;
            wsh[ch3][tap][co] = w_off[(co * C_ + cbase + ch3) * 9 + tap];
        }
        __syncthreads();
#pragma unroll
        for (int ch = 0; ch < 8; ++ch) {
#pragma unroll
            for (int ky = 0; ky < 3; ++ky) {
                float2 xv01 = *(float2*)&xs[ch][row + ky][cb];
                float2 xv23 = *(float2*)&xs[ch][row + ky][cb + 2];
                float xa[4] = {xv01.x, xv01.y, xv23.x, xv23.y};
#pragma unroll
                for (int kx = 0; kx < 3; ++kx) {
                    float4 w0 = *(float4*)&wsh[ch][ky * 3 + kx][0];
                    float4 w1 = *(float4*)&wsh[ch][ky * 3 + kx][4];
                    float wv[8] = {w0.x, w0.y, w0.z, w0.w, w1.x, w1.y, w1.z, w1.w};
                    float x0 = xa[kx], x1 = xa[kx + 1];
#pragma unroll
                    for (int co = 0; co < 8; ++co) {
                        acc[co][0] += x0 * wv[co];
                        acc[co][1] += x1 * wv[co];
                    }
                }
            }
        }
    }
#pragma unroll
    for (int co = 0; co < 8; ++co) {
        float2 v = make_float2(acc[co][0], acc[co][1]);
        *(float2*)&part[((size_t)(cc * BN_ + b) * 8 + co) * HW_ + (row0 + row) * W_ + cb] = v;
    }
}

// ---------------------------------------------------------------------------
// Kernel 2: reduce 8 partials + bias + tanh -> off
// ---------------------------------------------------------------------------
__global__ void off_reduce(const float* __restrict__ part, const float* __restrict__ b_off,
                           float* __restrict__ off) {
    int i = (blockIdx.x * 256 + threadIdx.x) * 4;
    if (i >= NOFF_) return;
    float4 s = *(const float4*)&part[i];
#pragma unroll
    for (int j = 1; j < 8; ++j) {
        float4 a = *(const float4*)&part[(size_t)j * NOFF_ + i];
        s.x += a.x; s.y += a.y; s.z += a.z; s.w += a.w;
    }
    int co = (i / HW_) & 7;
    float bb = b_off[co];
    float4 r;
    r.x = tanhf(s.x + bb);
    r.y = tanhf(s.y + bb);
    r.z = tanhf(s.z + bb);
    r.w = tanhf(s.w + bb);
    *(float4*)&off[i] = r;
}

// ---------------------------------------------------------------------------
// Kernel 3: 1x1 conv + folded BN + SiLU -> p.
// Grid 1024 = 16 b x 64 pos-tiles(64 pos). Block = 128 co x 64 pos.
// Thread = 8 co x 4 pos. 12 KB LDS -> ~4 blocks/CU.
// ---------------------------------------------------------------------------
__global__ __launch_bounds__(256) void conv_proj(const float* __restrict__ x,
                                                 const float* __restrict__ wT,
                                                 const float* __restrict__ b2,
                                                 float* __restrict__ p) {
    int bx = blockIdx.x;            // 1024 blocks
    int b = bx >> 6;
    int pos0 = (bx & 63) * 64;
    int t = threadIdx.x;
    int cob = (t >> 4) * 8;         // 0..120
    int pb  = (t & 15) * 4;         // 0..60

    __shared__ float xs[16][64];
    __shared__ float wsh[16][128];

    float acc[8][4];
#pragma unroll
    for (int i = 0; i < 8; ++i)
#pragma unroll
        for (int j = 0; j < 4; ++j) acc[i][j] = 0.f;

    int ks = t >> 4;                // 0..15 (staging k)
    int ps = (t & 15) * 4;          // staging pos quad

    for (int k0 = 0; k0 < C_; k0 += 16) {
        __syncthreads();
        *(float4*)&xs[ks][ps] = *(const float4*)&x[(size_t)(b * C_ + k0 + ks) * HW_ + pos0 + ps];
        int co8 = (t & 15) * 8;
        *(float4*)&wsh[ks][co8]     = *(const float4*)&wT[(k0 + ks) * C_ + co8];
        *(float4*)&wsh[ks][co8 + 4] = *(const float4*)&wT[(k0 + ks) * C_ + co8 + 4];
        __syncthreads();
#pragma unroll
        for (int k = 0; k < 16; ++k) {
            float4 xv = *(float4*)&xs[k][pb];
            float4 w0 = *(float4*)&wsh[k][cob];
            float4 w1 = *(float4*)&wsh[k][cob + 4];
            float wa[8] = {w0.x, w0.y, w0.z, w0.w, w1.x, w1.y, w1.z, w1.w};
#pragma unroll
            for (int co = 0; co < 8; ++co) {
                acc[co][0] += wa[co] * xv.x;
                acc[co][1] += wa[co] * xv.y;
                acc[co][2] += wa[co] * xv.z;
                acc[co][3] += wa[co] * xv.w;
            }
        }
    }
#pragma unroll
    for (int co = 0; co < 8; ++co) {
        float bb = b2[cob + co];
        float v[4];
#pragma unroll
        for (int j = 0; j < 4; ++j) {
            float a = acc[co][j] + bb;
            v[j] = a / (1.f + __expf(-a));
        }
        *(float4*)&p[(size_t)(b * C_ + cob + co) * HW_ + pos0 + pb] =
            make_float4(v[0], v[1], v[2], v[3]);
    }
}

// ---------------------------------------------------------------------------
// Kernel 4: upsample offsets + grid_sample via LDS-staged 3-row slab.
// Offsets are tanh-bounded (±0.492 input px) and base row position for
// output rows {2rp,2rp+1} is within ±0.496 of rp, so iy in [rp-0.99,rp+0.99]
// -> sampled input rows are rp-1..rp+1 only. Stage those 3 rows x 32 ch
// (24 KB) -> gathers become ~conflict-free ds_read_b32.
// Grid 4096 = 16 b x 4 g x 64 row-pairs; block 256 = 2 rows x 128 xs.
// ---------------------------------------------------------------------------
__global__ __launch_bounds__(256) void dysample(const float* __restrict__ p,
                                                const float* __restrict__ off,
                                                float* __restrict__ out) {
    int bx = blockIdx.x;
    int rp = bx & 63;
    int g  = (bx >> 6) & 3;
    int b  = bx >> 8;
    int t  = threadIdx.x;

    __shared__ float ls[CG_][3][64];   // 24 KB

    // stage rows rp-1..rp+1 (row-clamped) of the 32-channel group slab
    const float* pg = p + (size_t)(b * C_ + g * CG_) * HW_;
#pragma unroll
    for (int it = 0; it < 6; ++it) {
        int f = it * 256 + t;          // 0..1535 = 32ch * 3rows * 16 quads
        int ch = f / 48;
        int rem = f - ch * 48;
        int rw_ = rem >> 4;
        int wq = (rem & 15) << 2;
        int grow = min(max(rp - 1 + rw_, 0), 63);
        float4 v = *(const float4*)&pg[(size_t)ch * HW_ + grow * 64 + wq];
        *(float4*)&ls[ch][rw_][wq] = v;
    }

    int ys = rp * 2 + (t >> 7);
    int xsid = t & 127;

    // bilinear-upsample the two offset planes at (ys, xsid)
    const float rw = 63.0f / 127.0f;
    float py = ys * rw;
    int uy0 = (int)floorf(py);
    float fy = py - (float)uy0;
    int uy1 = min(uy0 + 1, 63);
    float pxf = xsid * rw;
    int ux0 = (int)floorf(pxf);
    float fx = pxf - (float)ux0;
    int ux1 = min(ux0 + 1, 63);

    const float* o0 = off + (size_t)(b * 8 + 2 * g) * HW_;
    const float* o1 = o0 + HW_;
    float ox, oy;
    {
        float a00 = o0[uy0 * 64 + ux0], a01 = o0[uy0 * 64 + ux1];
        float a10 = o0[uy1 * 64 + ux0], a11 = o0[uy1 * 64 + ux1];
        float t0 = a00 * (1.f - fy) + a10 * fy;
        float t1 = a01 * (1.f - fy) + a11 * fy;
        ox = t0 * (1.f - fx) + t1 * fx;
    }
    {
        float a00 = o1[uy0 * 64 + ux0], a01 = o1[uy0 * 64 + ux1];
        float a10 = o1[uy1 * 64 + ux0], a11 = o1[uy1 * 64 + ux1];
        float t0 = a00 * (1.f - fy) + a10 * fy;
        float t1 = a01 * (1.f - fy) + a11 * fy;
        oy = t0 * (1.f - fx) + t1 * fx;
    }

    float gx = (-1.f + xsid * (2.0f / 127.0f)) + ox * (2.0f / 128.0f);
    float gy = (-1.f + ys   * (2.0f / 127.0f)) + oy * (2.0f / 128.0f);

    float ix = fminf(fmaxf((gx + 1.f) * 0.5f * 63.f, 0.f), 63.f);
    float iy = fminf(fmaxf((gy + 1.f) * 0.5f * 63.f, 0.f), 63.f);
    int sx0 = (int)floorf(ix);
    int sx1 = min(sx0 + 1, 63);
    float wx = ix - (float)sx0;
    int sy0 = (int)floorf(iy);
    float wy = iy - (float)sy0;

    int ry0 = sy0 - rp + 1;            // in {0,1} by the bound proof
    int ry1 = min(sy0 + 1, 63) - rp + 1;

    float w00 = (1.f - wx) * (1.f - wy), w01 = wx * (1.f - wy);
    float w10 = (1.f - wx) * wy,         w11 = wx * wy;

    __syncthreads();

    float* obase = out + (size_t)(b * C_ + g * CG_) * HWS_ + ys * WS_ + xsid;
#pragma unroll 8
    for (int c = 0; c < CG_; ++c) {
        float v00 = ls[c][ry0][sx0], v01 = ls[c][ry0][sx1];
        float v10 = ls[c][ry1][sx0], v11 = ls[c][ry1][sx1];
        float r = v00 * w00 + v01 * w01 + v10 * w10 + v11 * w11;
        __builtin_nontemporal_store(r, &obase[(size_t)c * HWS_]);
    }
}

// ---------------------------------------------------------------------------
extern "C" void kernel_launch(void* const* d_in, const int* in_sizes, int n_in,
                              void* d_out, int out_size, void* d_ws, size_t ws_size,
                              hipStream_t stream) {
    const float* x      = (const float*)d_in[0];
    const float* w_off  = (const float*)d_in[1];
    const float* b_off  = (const float*)d_in[2];
    const float* w_proj = (const float*)d_in[3];
    const float* bn_g   = (const float*)d_in[4];
    const float* bn_b   = (const float*)d_in[5];
    const float* bn_m   = (const float*)d_in[6];
    const float* bn_v   = (const float*)d_in[7];
    float* out = (float*)d_out;
    float* ws  = (float*)d_ws;

    // ws layout (floats). part (16MB) dead before p (32MB) written -> alias.
    float* p    = ws;                 // 8,388,608 floats
    float* part = ws;                 // 4,194,304 floats (aliased with p)
    float* offb = ws + 8388608;       //   524,288
    float* wT   = ws + 8912896;       //    16,384
    float* b2   = ws + 8929280;       //       128

    prep_w    <<<65,   256, 0, stream>>>(w_proj, bn_g, bn_b, bn_m, bn_v, wT, b2);
    conv_off  <<<1024, 256, 0, stream>>>(x, w_off, part);
    off_reduce<<<512,  256, 0, stream>>>(part, b_off, offb);
    conv_proj <<<1024, 256, 0, stream>>>(x, wT, b2, p);
    dysample  <<<4096, 256, 0, stream>>>(p, offb, out);
}